// Round 1
// baseline (351.816 us; speedup 1.0000x reference)
//
#include <hip/hip_runtime.h>

// BBoxGenerator: (256,1,512,512) fp32 mask -> (256,4) boxes [x0,y0,x1,y1].
// Memory-bound streaming reduction: one block per batch image.

constexpr int H = 512;
constexpr int W = 512;
constexpr int THREADS = 1024;   // 16 waves/block, 1 block/CU at B=256

__global__ __launch_bounds__(THREADS)
void bbox_kernel(const float* __restrict__ mask, float* __restrict__ out) {
    const int b = blockIdx.x;
    const float4* __restrict__ base =
        reinterpret_cast<const float4*>(mask) + (size_t)b * (H * W / 4);
    const int t = threadIdx.x;

    // Running extrema in registers. Inits match reference's masked-min/max
    // fill values: ys fill = H, xs fill = W, max fill = -1.
    int ymin = H, ymax = -1, xmin = W, xmax = -1;

    // 512*512/4 = 65536 float4s, / 1024 threads = 64 per thread.
    // Unroll 8-deep so 8 global_load_dwordx4 are in flight per wave.
    #pragma unroll
    for (int i = 0; i < 64; i += 8) {
        float4 v[8];
        #pragma unroll
        for (int j = 0; j < 8; ++j) v[j] = base[t + (i + j) * THREADS];
        #pragma unroll
        for (int j = 0; j < 8; ++j) {
            const int e = (t + (i + j) * THREADS) * 4;  // element index
            const int y = e >> 9;        // e / W
            const int x = e & (W - 1);   // e % W  (4 elems share a row)
            const bool a0 = v[j].x > 0.5f;
            const bool a1 = v[j].y > 0.5f;
            const bool a2 = v[j].z > 0.5f;
            const bool a3 = v[j].w > 0.5f;
            if (a0 | a1 | a2 | a3) { ymin = min(ymin, y); ymax = max(ymax, y); }
            if (a0) { xmin = min(xmin, x    ); xmax = max(xmax, x    ); }
            if (a1) { xmin = min(xmin, x + 1); xmax = max(xmax, x + 1); }
            if (a2) { xmin = min(xmin, x + 2); xmax = max(xmax, x + 2); }
            if (a3) { xmin = min(xmin, x + 3); xmax = max(xmax, x + 3); }
        }
    }

    // Wave (64-lane) butterfly reduction.
    #pragma unroll
    for (int off = 32; off > 0; off >>= 1) {
        ymin = min(ymin, __shfl_down(ymin, off));
        ymax = max(ymax, __shfl_down(ymax, off));
        xmin = min(xmin, __shfl_down(xmin, off));
        xmax = max(xmax, __shfl_down(xmax, off));
    }

    __shared__ int s_ymin[16], s_ymax[16], s_xmin[16], s_xmax[16];
    const int wave = t >> 6;
    if ((t & 63) == 0) {
        s_ymin[wave] = ymin; s_ymax[wave] = ymax;
        s_xmin[wave] = xmin; s_xmax[wave] = xmax;
    }
    __syncthreads();

    if (t == 0) {
        #pragma unroll
        for (int w = 1; w < 16; ++w) {
            ymin = min(ymin, s_ymin[w]); ymax = max(ymax, s_ymax[w]);
            xmin = min(xmin, s_xmin[w]); xmax = max(xmax, s_xmax[w]);
        }
        float x0, y0, x1, y1;
        if (ymax < 0) {
            // no foreground anywhere -> default box
            x0 = 0.25f; y0 = 0.25f; x1 = 0.75f; y1 = 0.75f;
        } else {
            y0 = (float)ymin * (1.0f / H);
            y1 = (float)ymax * (1.0f / H);
            x0 = (float)xmin * (1.0f / W);
            x1 = (float)xmax * (1.0f / W);
            const float s = 0.05f;
            if (x1 - x0 < s) {
                const float c = (x0 + x1) * 0.5f;
                x0 = fmaxf(0.0f, c - s * 0.5f);
                x1 = fminf(1.0f, c + s * 0.5f);
            }
            if (y1 - y0 < s) {
                const float c = (y0 + y1) * 0.5f;
                y0 = fmaxf(0.0f, c - s * 0.5f);
                y1 = fminf(1.0f, c + s * 0.5f);
            }
        }
        reinterpret_cast<float4*>(out)[b] = make_float4(x0, y0, x1, y1);
    }
}

extern "C" void kernel_launch(void* const* d_in, const int* in_sizes, int n_in,
                              void* d_out, int out_size, void* d_ws, size_t ws_size,
                              hipStream_t stream) {
    const float* mask = (const float*)d_in[0];
    float* out = (float*)d_out;
    const int B = in_sizes[0] / (H * W);   // 256
    bbox_kernel<<<B, THREADS, 0, stream>>>(mask, out);
}

// Round 2
// 302.892 us; speedup vs baseline: 1.1615x; 1.1615x over previous
//
#include <hip/hip_runtime.h>

// BBoxGenerator: (256,1,512,512) fp32 mask -> (256,4) boxes [x0,y0,x1,y1].
// Adaptive early-exit scan: only the first/last fg row and column matter.
// One block per image; four phases (ymin, ymax, xmin, xmax), each a
// group/strip scan with uniform block-wide early exit.

constexpr int H = 512;
constexpr int W = 512;
constexpr int THREADS = 1024;        // 16 waves
constexpr int NWAVE = THREADS / 64;
constexpr int BIG = 1 << 29;

__device__ __forceinline__ int block_min(int v, int t, int* s_tmp, int* s_res) {
    #pragma unroll
    for (int off = 32; off > 0; off >>= 1) v = min(v, __shfl_down(v, off));
    if ((t & 63) == 0) s_tmp[t >> 6] = v;
    __syncthreads();
    if (t == 0) {
        int m = s_tmp[0];
        #pragma unroll
        for (int w = 1; w < NWAVE; ++w) m = min(m, s_tmp[w]);
        *s_res = m;
    }
    __syncthreads();
    return *s_res;
}

__device__ __forceinline__ int block_max(int v, int t, int* s_tmp, int* s_res) {
    #pragma unroll
    for (int off = 32; off > 0; off >>= 1) v = max(v, __shfl_down(v, off));
    if ((t & 63) == 0) s_tmp[t >> 6] = v;
    __syncthreads();
    if (t == 0) {
        int m = s_tmp[0];
        #pragma unroll
        for (int w = 1; w < NWAVE; ++w) m = max(m, s_tmp[w]);
        *s_res = m;
    }
    __syncthreads();
    return *s_res;
}

__global__ __launch_bounds__(THREADS)
void bbox_kernel(const float* __restrict__ mask, float* __restrict__ out) {
    const int b = blockIdx.x;
    const float4* __restrict__ img =
        reinterpret_cast<const float4*>(mask) + (size_t)b * (H * W / 4);
    const int t = threadIdx.x;
    __shared__ int s_tmp[NWAVE];
    __shared__ int s_res;

    const int rg = t >> 7;   // row within an 8-row group   [0,8)
    const int cg = t & 127;  // float4 column within row    [0,128)
    const int rs = t >> 1;   // row for 8-col strips        [0,512)
    const int cs = t & 1;    // float4 within strip         [0,2)

    // ---- ymin: 8-row groups, top-down, early exit ----
    int ymin = BIG;
    for (int g = 0; g < H / 8; ++g) {
        const int r = g * 8 + rg;
        const float4 v = img[(r << 7) + cg];
        const bool fg = (v.x > 0.5f) || (v.y > 0.5f) || (v.z > 0.5f) || (v.w > 0.5f);
        const int res = block_min(fg ? r : BIG, t, s_tmp, &s_res);
        if (res < BIG) { ymin = res; break; }
    }
    if (ymin >= BIG) {  // no foreground anywhere
        if (t == 0)
            reinterpret_cast<float4*>(out)[b] = make_float4(0.25f, 0.25f, 0.75f, 0.75f);
        return;
    }

    // ---- ymax: 8-row groups, bottom-up (>= ymin's group guaranteed) ----
    int ymax = -1;
    for (int g = H / 8 - 1; g >= (ymin >> 3); --g) {
        const int r = g * 8 + rg;
        const float4 v = img[(r << 7) + cg];
        const bool fg = (v.x > 0.5f) || (v.y > 0.5f) || (v.z > 0.5f) || (v.w > 0.5f);
        const int res = block_max(fg ? r : -1, t, s_tmp, &s_res);
        if (res >= 0) { ymax = res; break; }
    }

    // ---- xmin: 8-col strips (2 float4 x 512 rows), left -> right ----
    int xmin = BIG;
    for (int s = 0; s < W / 8; ++s) {
        const int c4 = s * 2 + cs;
        const float4 v = img[(rs << 7) + c4];
        const int c = c4 * 4;
        int cand = BIG;
        if (v.w > 0.5f) cand = c + 3;
        if (v.z > 0.5f) cand = c + 2;
        if (v.y > 0.5f) cand = c + 1;
        if (v.x > 0.5f) cand = c;
        const int res = block_min(cand, t, s_tmp, &s_res);
        if (res < BIG) { xmin = res; break; }
    }

    // ---- xmax: 8-col strips, right -> left (>= xmin's strip guaranteed) ----
    int xmax = -1;
    for (int s = W / 8 - 1; s >= (xmin >> 3); --s) {
        const int c4 = s * 2 + cs;
        const float4 v = img[(rs << 7) + c4];
        const int c = c4 * 4;
        int cand = -1;
        if (v.x > 0.5f) cand = c;
        if (v.y > 0.5f) cand = c + 1;
        if (v.z > 0.5f) cand = c + 2;
        if (v.w > 0.5f) cand = c + 3;
        const int res = block_max(cand, t, s_tmp, &s_res);
        if (res >= 0) { xmax = res; break; }
    }

    if (t == 0) {
        float y0 = (float)ymin * (1.0f / H);
        float y1 = (float)ymax * (1.0f / H);
        float x0 = (float)xmin * (1.0f / W);
        float x1 = (float)xmax * (1.0f / W);
        const float s = 0.05f;
        if (x1 - x0 < s) {
            const float c = (x0 + x1) * 0.5f;
            x0 = fmaxf(0.0f, c - s * 0.5f);
            x1 = fminf(1.0f, c + s * 0.5f);
        }
        if (y1 - y0 < s) {
            const float c = (y0 + y1) * 0.5f;
            y0 = fmaxf(0.0f, c - s * 0.5f);
            y1 = fminf(1.0f, c + s * 0.5f);
        }
        reinterpret_cast<float4*>(out)[b] = make_float4(x0, y0, x1, y1);
    }
}

extern "C" void kernel_launch(void* const* d_in, const int* in_sizes, int n_in,
                              void* d_out, int out_size, void* d_ws, size_t ws_size,
                              hipStream_t stream) {
    const float* mask = (const float*)d_in[0];
    float* out = (float*)d_out;
    const int B = in_sizes[0] / (H * W);  // 256
    bbox_kernel<<<B, THREADS, 0, stream>>>(mask, out);
}

// Round 3
// 300.039 us; speedup vs baseline: 1.1726x; 1.0095x over previous
//
#include <hip/hip_runtime.h>

// BBoxGenerator: (256,1,512,512) fp32 mask -> (256,4) boxes [x0,y0,x1,y1].
// R3: phase-parallel early-exit scan. Grid (B,4): one block per (image,
// extremum). Each block scans 4-row groups (y) or 4-col strips (x) with a
// block-uniform early exit, writes its raw extremum to d_ws. A second tiny
// kernel applies the expand/empty epilogue. Max-phases reduce min(-key) so
// one reducer serves all four phases.

constexpr int H = 512;
constexpr int W = 512;
constexpr int THREADS = 512;          // 8 waves
constexpr int NWAVE = THREADS / 64;
constexpr int BIG = 1 << 29;          // sentinel: "nothing found"

__device__ __forceinline__ int block_min(int v, int t, int* s_tmp, int* s_res) {
    #pragma unroll
    for (int off = 32; off > 0; off >>= 1) v = min(v, __shfl_down(v, off));
    if ((t & 63) == 0) s_tmp[t >> 6] = v;
    __syncthreads();
    if (t == 0) {
        int m = s_tmp[0];
        #pragma unroll
        for (int w = 1; w < NWAVE; ++w) m = min(m, s_tmp[w]);
        *s_res = m;
    }
    __syncthreads();
    return *s_res;
}

__global__ __launch_bounds__(THREADS)
void scan_kernel(const float* __restrict__ mask, int* __restrict__ ws) {
    const int b = blockIdx.x;
    const int phase = blockIdx.y;  // 0:ymin 1:ymax 2:xmin 3:xmax
    const float4* __restrict__ img =
        reinterpret_cast<const float4*>(mask) + (size_t)b * (H * W / 4);
    const int t = threadIdx.x;
    __shared__ int s_tmp[NWAVE];
    __shared__ int s_res;

    int result = BIG;

    if (phase < 2) {
        // 4-row groups: 4 rows x 128 float4 = 512 threads per probe.
        const int rr = t >> 7;       // row within group [0,4)
        const int c4 = t & 127;      // float4 col       [0,128)
        for (int g = 0; g < H / 4; ++g) {
            const int gg = (phase == 0) ? g : (H / 4 - 1 - g);
            const int r = gg * 4 + rr;
            const float4 v = img[(r << 7) + c4];
            const bool fg = (v.x > 0.5f) || (v.y > 0.5f) ||
                            (v.z > 0.5f) || (v.w > 0.5f);
            const int key = fg ? (phase == 0 ? r : -r) : BIG;
            const int res = block_min(key, t, s_tmp, &s_res);
            if (res < BIG) { result = res; break; }
        }
    } else {
        // 4-col strips: one float4 per row x 512 rows = 512 threads per probe.
        const int r = t;             // row [0,512)
        for (int s = 0; s < W / 4; ++s) {
            const int ss = (phase == 2) ? s : (W / 4 - 1 - s);
            const float4 v = img[(r << 7) + ss];
            const int c = ss * 4;
            int key = BIG;
            if (phase == 2) {        // leftmost fg col in this float4
                if (v.w > 0.5f) key = c + 3;
                if (v.z > 0.5f) key = c + 2;
                if (v.y > 0.5f) key = c + 1;
                if (v.x > 0.5f) key = c;
            } else {                 // rightmost, negated for min-reduce
                if (v.x > 0.5f) key = -c;
                if (v.y > 0.5f) key = -(c + 1);
                if (v.z > 0.5f) key = -(c + 2);
                if (v.w > 0.5f) key = -(c + 3);
            }
            const int res = block_min(key, t, s_tmp, &s_res);
            if (res < BIG) { result = res; break; }
        }
    }

    if (t == 0) ws[b * 4 + phase] = result;   // BIG sentinel if empty
}

__global__ __launch_bounds__(256)
void box_kernel(const int* __restrict__ ws, float* __restrict__ out, int B) {
    const int b = blockIdx.x * blockDim.x + threadIdx.x;
    if (b >= B) return;
    const int ymin = ws[b * 4 + 0];
    const int nymax = ws[b * 4 + 1];
    const int xmin = ws[b * 4 + 2];
    const int nxmax = ws[b * 4 + 3];
    float x0, y0, x1, y1;
    if (ymin >= BIG) {
        x0 = 0.25f; y0 = 0.25f; x1 = 0.75f; y1 = 0.75f;
    } else {
        const int ymax = -nymax, xmax = -nxmax;
        y0 = (float)ymin * (1.0f / H);
        y1 = (float)ymax * (1.0f / H);
        x0 = (float)xmin * (1.0f / W);
        x1 = (float)xmax * (1.0f / W);
        const float s = 0.05f;
        if (x1 - x0 < s) {
            const float c = (x0 + x1) * 0.5f;
            x0 = fmaxf(0.0f, c - s * 0.5f);
            x1 = fminf(1.0f, c + s * 0.5f);
        }
        if (y1 - y0 < s) {
            const float c = (y0 + y1) * 0.5f;
            y0 = fmaxf(0.0f, c - s * 0.5f);
            y1 = fminf(1.0f, c + s * 0.5f);
        }
    }
    reinterpret_cast<float4*>(out)[b] = make_float4(x0, y0, x1, y1);
}

extern "C" void kernel_launch(void* const* d_in, const int* in_sizes, int n_in,
                              void* d_out, int out_size, void* d_ws, size_t ws_size,
                              hipStream_t stream) {
    const float* mask = (const float*)d_in[0];
    float* out = (float*)d_out;
    int* ws = (int*)d_ws;
    const int B = in_sizes[0] / (H * W);  // 256
    dim3 grid(B, 4);
    scan_kernel<<<grid, THREADS, 0, stream>>>(mask, ws);
    box_kernel<<<(B + 255) / 256, 256, 0, stream>>>(ws, out, B);
}